// Round 14
// baseline (123.658 us; speedup 1.0000x reference)
//
#include <hip/hip_runtime.h>
#include <math.h>

#define BB 8
#define CC 32
#define TT 9
#define LL 512
#define HH 8
#define DD 4
#define NBT (BB*TT)          // 72
#define RELN (2*LL-1)        // 1023
#define RLN2 1.4426950408889634f

typedef float  f4v __attribute__((ext_vector_type(4)));
typedef int    i4v __attribute__((ext_vector_type(4)));
typedef short  s8v __attribute__((ext_vector_type(8)));   // 8 bf16 = 4 VGPRs

#define EXP2(x) __builtin_amdgcn_exp2f(x)   // raw v_exp_f32

__device__ __forceinline__ unsigned cvtpk(float lo, float hi) {
  unsigned u;
  asm("v_cvt_pk_bf16_f32 %0, %1, %2" : "=v"(u) : "v"(lo), "v"(hi));
  return u;
}

// ---- mixed bias, reversed + log2e-prescaled
__global__ void mixed_bias_kernel(const float* __restrict__ rpb,
                                  const float* __restrict__ Wl,
                                  float* __restrict__ mbr) {
  int x = blockIdx.x * blockDim.x + threadIdx.x;
  if (x >= RELN) return;
  int idx = 1022 - x;
  float r[HH];
  #pragma unroll
  for (int h = 0; h < HH; ++h) r[h] = rpb[h*RELN + idx];
  #pragma unroll
  for (int Ho = 0; Ho < HH; ++Ho) {
    float acc = 0.f;
    #pragma unroll
    for (int h = 0; h < HH; ++h) acc += r[h] * Wl[h*HH + Ho];
    mbr[Ho*1024 + x] = RLN2 * acc;
  }
}

// ---------------- transpose pl_w (512x512) ----------------
__global__ __launch_bounds__(256) void transpose512_kernel(const float* __restrict__ in,
                                                           float* __restrict__ outT) {
  __shared__ float tile[32][33];
  int bx = blockIdx.x * 32, by = blockIdx.y * 32;
  int tx = threadIdx.x & 31, ty = threadIdx.x >> 5;   // 32x8
  #pragma unroll
  for (int yy = ty; yy < 32; yy += 8)
    tile[yy][tx] = in[(by + yy)*LL + bx + tx];
  __syncthreads();
  #pragma unroll
  for (int yy = ty; yy < 32; yy += 8)
    outT[(bx + yy)*LL + by + tx] = tile[tx][yy];
}

// ---------------- q/k/v projection + l2norm (4-way co-split) ----------------
__global__ __launch_bounds__(256) void proj_kernel(
    const float* __restrict__ x,
    const float* __restrict__ Wq, const float* __restrict__ bq,
    const float* __restrict__ Wk, const float* __restrict__ bk,
    const float* __restrict__ Wv, const float* __restrict__ bv,
    float* __restrict__ qo, short* __restrict__ kbo, float* __restrict__ vbo) {
  int gidx = blockIdx.x * 256 + threadIdx.x;    // 0..36863
  int l  = gidx & (LL-1);
  int bt = gidx >> 9;
  int b = bt / TT, t = bt - b*TT;
  const int hq = blockIdx.y * 2;

  float xv[CC];
  #pragma unroll
  for (int c = 0; c < CC; ++c)
    xv[c] = x[((b*CC + c)*TT + t)*LL + l];

  // Q (scaled by 0.5*log2e)
  #pragma unroll
  for (int h = hq; h < hq + 2; ++h) {
    float yv[DD];
    #pragma unroll
    for (int d = 0; d < DD; ++d) {
      int co = h*DD + d;
      float acc = bq[co];
      #pragma unroll
      for (int ci = 0; ci < CC; ++ci) acc += xv[ci] * Wq[co*CC + ci];
      yv[d] = acc;
    }
    float n = sqrtf(yv[0]*yv[0] + yv[1]*yv[1] + yv[2]*yv[2] + yv[3]*yv[3]);
    float inv = 0.5f * RLN2 / fmaxf(n, 1e-12f);
    *reinterpret_cast<float4*>(&qo[((size_t)bt*LL + l)*CC + h*DD]) =
        make_float4(yv[0]*inv, yv[1]*inv, yv[2]*inv, yv[3]*inv);
  }
  // K -> bf16
  {
    unsigned ku[4];
    #pragma unroll
    for (int hh = 0; hh < 2; ++hh) {
      int h = hq + hh;
      float yv[DD];
      #pragma unroll
      for (int d = 0; d < DD; ++d) {
        int co = h*DD + d;
        float acc = bk[co];
        #pragma unroll
        for (int ci = 0; ci < CC; ++ci) acc += xv[ci] * Wk[co*CC + ci];
        yv[d] = acc;
      }
      float n = sqrtf(yv[0]*yv[0] + yv[1]*yv[1] + yv[2]*yv[2] + yv[3]*yv[3]);
      float inv = 1.0f / fmaxf(n, 1e-12f);
      ku[hh*2]   = cvtpk(yv[0]*inv, yv[1]*inv);
      ku[hh*2+1] = cvtpk(yv[2]*inv, yv[3]*inv);
    }
    *reinterpret_cast<uint4*>(kbo + ((size_t)bt*LL + l)*CC + hq*DD) =
        make_uint4(ku[0], ku[1], ku[2], ku[3]);
  }
  // V fp32
  #pragma unroll
  for (int h = hq; h < hq + 2; ++h) {
    float yv[DD];
    #pragma unroll
    for (int d = 0; d < DD; ++d) {
      int co = h*DD + d;
      float acc = bv[co];
      #pragma unroll
      for (int ci = 0; ci < CC; ++ci) acc += xv[ci] * Wv[co*CC + ci];
      yv[d] = acc;
    }
    float n = sqrtf(yv[0]*yv[0] + yv[1]*yv[1] + yv[2]*yv[2] + yv[3]*yv[3]);
    float inv = 1.0f / fmaxf(n, 1e-12f);
    *reinterpret_cast<float4*>(&vbo[((size_t)bt*LL + l)*CC + h*DD]) =
        make_float4(yv[0]*inv, yv[1]*inv, yv[2]*inv, yv[3]*inv);
  }
}

// ---------------- Vt: VbT[bt][n=32][j=512] bf16; grid (72,4) ----------------
__global__ __launch_bounds__(256) void vbt_kernel(const float* __restrict__ vbo,
                                                  short* __restrict__ vt) {
  int bt = blockIdx.x;
  int qq = blockIdx.y;
  int n  = threadIdx.x & 31;
  int sub = threadIdx.x >> 5;
  int j0 = qq*128 + sub*16;
  const float* src = vbo + ((size_t)bt*LL)*CC + n;
  unsigned u[8];
  #pragma unroll
  for (int jj = 0; jj < 8; ++jj) {
    float a = src[(size_t)(j0 + 2*jj)*CC];
    float b = src[(size_t)(j0 + 2*jj + 1)*CC];
    u[jj] = cvtpk(a, b);
  }
  uint4* dst = reinterpret_cast<uint4*>(vt + ((size_t)bt*CC + n)*LL + j0);
  dst[0] = make_uint4(u[0], u[1], u[2], u[3]);
  dst[1] = make_uint4(u[4], u[5], u[6], u[7]);
}

// ---------------- fused attention + Wm (v14: j-split waves, prefetch) ----------------
// 2304 blocks x 256 thr. Block = (bt, 16-row i-tile). Wave w: Hh=w&1 (heads Hh*4..+3),
// jh=(w>>1)&1 (j in [jh*256, jh*256+256)). Per wave: 8 jp windows, K/V prefetched one
// jp ahead. Softmax denom combined across j-halves via sden LDS; PV/mix2 partials are
// linear -> combined in xch stage (3 slots). Epilogue: x_att tile -> in-block Wm.
__global__ __launch_bounds__(256, 2) void attn_kernel(
    const float* __restrict__ q, const short* __restrict__ kb,
    const short* __restrict__ vt,
    const float* __restrict__ Wl, const float* __restrict__ Wc,
    const float* __restrict__ mbr,
    const float* __restrict__ Wm, const float* __restrict__ bm,
    float* __restrict__ out, float* __restrict__ xm8) {
  __shared__ float sden[2][2][4][16];   // [jh][Hh][hh][i]
  __shared__ float xch[3][64][9];       // non-leader partials, padded
  __shared__ float xt[16][33];          // x_att tile, padded
  __shared__ float sWm[32][33];
  __shared__ float sbm[32];

  const int wgid = blockIdx.x;
  const int id   = (wgid & 7) * 288 + (wgid >> 3);   // 2304 % 8 == 0 -> bijective
  const int bt   = id >> 5;       // [0,72)
  const int iblk = id & 31;       // 16-row tile
  const int b    = bt / TT, t = bt - b*TT;

  const int tid  = threadIdx.x;
  const int w    = __builtin_amdgcn_readfirstlane(tid >> 6);
  const int lane = tid & 63;
  const int g    = lane >> 4;     // 0..3
  const int c16  = lane & 15;
  const int it   = iblk*16;
  const int Hh   = w & 1;
  const int jh   = (w >> 1) & 1;
  const int Hb   = Hh*4;
  const int jwb  = jh*256;

  // preload Wm/bm -> LDS (visible after first barrier)
  {
    int c4 = tid * 4;
    int co = c4 >> 5, ci = c4 & 31;
    float4 wv = *reinterpret_cast<const float4*>(Wm + co*CC + ci);
    sWm[co][ci] = wv.x; sWm[co][ci+1] = wv.y; sWm[co][ci+2] = wv.z; sWm[co][ci+3] = wv.w;
    if (tid < 32) sbm[tid] = bm[tid];
  }

  // build 4 QM b-frags: B[k=c][n=i] = Wl[h(c)][H] * q[i][c]
  s8v bq4[4];
  {
    float qp[8];
    const float* qr = q + ((size_t)bt*LL + it + c16)*CC + g*8;
    float4 qa = *reinterpret_cast<const float4*>(qr);
    float4 qb = *reinterpret_cast<const float4*>(qr + 4);
    qp[0]=qa.x; qp[1]=qa.y; qp[2]=qa.z; qp[3]=qa.w;
    qp[4]=qb.x; qp[5]=qb.y; qp[6]=qb.z; qp[7]=qb.w;
    const int h0 = g*2;
    #pragma unroll
    for (int hh = 0; hh < 4; ++hh) {
      const int H = Hb + hh;
      const float wla = Wl[h0*HH + H];
      const float wlb = Wl[(h0+1)*HH + H];
      i4v uq;
      uq[0] = (int)cvtpk(qp[0]*wla, qp[1]*wla);
      uq[1] = (int)cvtpk(qp[2]*wla, qp[3]*wla);
      uq[2] = (int)cvtpk(qp[4]*wlb, qp[5]*wlb);
      uq[3] = (int)cvtpk(qp[6]*wlb, qp[7]*wlb);
      bq4[hh] = __builtin_bit_cast(s8v, uq);
    }
  }

  const short* kbase = kb + ((size_t)bt*LL)*CC + (size_t)c16*CC + g*8;
  const short* vb0 = vt + ((size_t)bt*CC)*LL + (size_t)c16*LL + 8*g;
  const short* vb1 = vb0 + 16*LL;
  const float* mbase = mbr + Hb*1024 + 511 + 4*g - it - c16;

  f4v t0[4], t1[4];
  float den[4];
  #pragma unroll
  for (int hh = 0; hh < 4; ++hh) {
    t0[hh] = (f4v){0.f,0.f,0.f,0.f};
    t1[hh] = (f4v){0.f,0.f,0.f,0.f};
    den[hh] = 0.f;
  }

  const int s0b = (c16 + 32*(g & 1))*4;
  const int s1b = s0b + 64;
  const bool useA = (g < 2);

  // prefetch jp=0
  s8v ak0 = *reinterpret_cast<const s8v*>(kbase + (size_t)jwb*CC);
  s8v ak1 = *reinterpret_cast<const s8v*>(kbase + (size_t)(jwb+16)*CC);
  s8v v0  = *reinterpret_cast<const s8v*>(vb0 + jwb);
  s8v v1  = *reinterpret_cast<const s8v*>(vb1 + jwb);

  #pragma unroll 1
  for (int jp = 0; jp < 8; ++jp) {
    const int j0 = jwb + jp*32;
    s8v nk0, nk1, nv0, nv1;
    if (jp < 7) {   // prefetch next window
      nk0 = *reinterpret_cast<const s8v*>(kbase + (size_t)(j0+32)*CC);
      nk1 = *reinterpret_cast<const s8v*>(kbase + (size_t)(j0+48)*CC);
      nv0 = *reinterpret_cast<const s8v*>(vb0 + j0 + 32);
      nv1 = *reinterpret_cast<const s8v*>(vb1 + j0 + 32);
    }

    #pragma unroll
    for (int hh = 0; hh < 4; ++hh) {
      const float* m = mbase + hh*1024 + j0;
      unsigned uA0, uA1, uB0, uB1;
      {
        f4v cb = { m[0], m[1], m[2], m[3] };
        f4v d = __builtin_amdgcn_mfma_f32_16x16x32_bf16(ak0, bq4[hh], cb, 0, 0, 0);
        float e0 = EXP2(d[0]), e1 = EXP2(d[1]), e2 = EXP2(d[2]), e3 = EXP2(d[3]);
        den[hh] += (e0 + e1) + (e2 + e3);
        uA0 = cvtpk(e0, e1); uA1 = cvtpk(e2, e3);
      }
      {
        f4v cb = { m[16], m[17], m[18], m[19] };
        f4v d = __builtin_amdgcn_mfma_f32_16x16x32_bf16(ak1, bq4[hh], cb, 0, 0, 0);
        float e0 = EXP2(d[0]), e1 = EXP2(d[1]), e2 = EXP2(d[2]), e3 = EXP2(d[3]);
        den[hh] += (e0 + e1) + (e2 + e3);
        uB0 = cvtpk(e0, e1); uB1 = cvtpk(e2, e3);
      }
      int a00 = __builtin_amdgcn_ds_bpermute(s0b, (int)uA0);
      int b00 = __builtin_amdgcn_ds_bpermute(s0b, (int)uB0);
      int a01 = __builtin_amdgcn_ds_bpermute(s0b, (int)uA1);
      int b01 = __builtin_amdgcn_ds_bpermute(s0b, (int)uB1);
      int a10 = __builtin_amdgcn_ds_bpermute(s1b, (int)uA0);
      int b10 = __builtin_amdgcn_ds_bpermute(s1b, (int)uB0);
      int a11 = __builtin_amdgcn_ds_bpermute(s1b, (int)uA1);
      int b11 = __builtin_amdgcn_ds_bpermute(s1b, (int)uB1);
      i4v pv;
      pv[0] = useA ? a00 : b00;
      pv[1] = useA ? a01 : b01;
      pv[2] = useA ? a10 : b10;
      pv[3] = useA ? a11 : b11;
      s8v pa = __builtin_bit_cast(s8v, pv);
      t0[hh] = __builtin_amdgcn_mfma_f32_16x16x32_bf16(pa, v0, t0[hh], 0, 0, 0);
      t1[hh] = __builtin_amdgcn_mfma_f32_16x16x32_bf16(pa, v1, t1[hh], 0, 0, 0);
    }
    ak0 = nk0; ak1 = nk1; v0 = nv0; v1 = nv1;
  }

  // ---- denominator partials: in-wave reduce, then cross-j-half combine via LDS
  float dnred[4];
  #pragma unroll
  for (int hh = 0; hh < 4; ++hh) {
    float dn = den[hh];
    dn += __shfl_xor(dn, 16);
    dn += __shfl_xor(dn, 32);
    dnred[hh] = dn;
  }
  if (lane < 16) {
    #pragma unroll
    for (int hh = 0; hh < 4; ++hh)
      sden[jh][Hh][hh][lane] = dnred[hh];
  }
  __syncthreads();

  // ---- scale partials by Wc/S
  f4v fin0 = {0.f,0.f,0.f,0.f}, fin1 = {0.f,0.f,0.f,0.f};
  #pragma unroll
  for (int hh = 0; hh < 4; ++hh) {
    const int H = Hb + hh;
    float inv = __builtin_amdgcn_rcpf(dnred[hh] + sden[jh^1][Hh][hh][c16]);
    const float wclo = Wc[H*HH + (c16 >> 2)];
    const float wchi = Wc[H*HH + 4 + (c16 >> 2)];
    #pragma unroll
    for (int r = 0; r < 4; ++r) {
      float ir = __int_as_float(
          __builtin_amdgcn_ds_bpermute((4*g + r)*4, __float_as_int(inv)));
      fin0[r] += t0[hh][r] * (ir * wclo);
      fin1[r] += t1[hh][r] * (ir * wchi);
    }
  }

  // ---- combine 4 wave-partials (Hh x jh): waves 1..3 write, wave 0 sums
  if (w > 0) {
    #pragma unroll
    for (int r = 0; r < 4; ++r) {
      xch[w-1][lane][r]     = fin0[r];
      xch[w-1][lane][4 + r] = fin1[r];
    }
  }
  __syncthreads();
  if (w == 0) {
    #pragma unroll
    for (int r = 0; r < 4; ++r) {
      float o0 = fin0[r] + xch[0][lane][r] + xch[1][lane][r] + xch[2][lane][r];
      float o1 = fin1[r] + xch[0][lane][4+r] + xch[1][lane][4+r] + xch[2][lane][4+r];
      const int row = 4*g + r;
      xt[row][c16]      = o0;
      xt[row][16 + c16] = o1;
    }
  }
  __syncthreads();

  // ---- in-block Wm: 512 outputs over 256 threads (2 co each, one row)
  {
    const int row = tid & 15;
    const int cos = (tid >> 4) * 2;
    float a0 = sbm[cos], a1 = sbm[cos+1];
    #pragma unroll
    for (int c = 0; c < CC; ++c) {
      float xv = xt[row][c];
      a0 += xv * sWm[cos][c];
      a1 += xv * sWm[cos+1][c];
    }
    const int l = it + row;
    if (t < TT-1) {
      out[((b*CC + cos)*TT + t)*LL + l]     = a0;
      out[((b*CC + cos+1)*TT + t)*LL + l]   = a1;
    } else {
      xm8[(b*CC + cos)*LL + l]   = a0;
      xm8[(b*CC + cos+1)*LL + l] = a1;
    }
  }
}

// ---------------- fused conv+BN+ReLU+token-linear+subtract (1024 thr, 2-way split) --------
__global__ __launch_bounds__(1024) void convpl_kernel(
    const float* __restrict__ out_in, const float* __restrict__ pp,
    const float* __restrict__ cw, const float* __restrict__ cb,
    const float* __restrict__ bng, const float* __restrict__ bnb,
    const float* __restrict__ plwT, const float* __restrict__ plb,
    const float* __restrict__ xm8, float* __restrict__ out) {
  __shared__ float sy[LL];
  __shared__ float part[2][LL];
  int bc = blockIdx.x;            // b*32 + co
  int b = bc >> 5, co = bc & 31;
  int tid = threadIdx.x;
  int l = tid & (LL-1);
  int h = tid >> 9;               // 0,1

  float acc = (h == 0) ? cb[co] : 0.f;
  #pragma unroll
  for (int cc = 0; cc < 16; ++cc) {
    int ci = h*16 + cc;
    const float* base = out_in + ((b*CC + ci)*TT)*LL + l;
    const float* wv = cw + (co*CC + ci)*TT;
    #pragma unroll
    for (int tq = 0; tq < TT-1; ++tq) acc += base[tq*LL] * wv[tq];
    acc += pp[ci*LL + l] * wv[TT-1];
  }
  part[h][l] = acc;
  __syncthreads();
  if (h == 0) {
    float scale = bng[co] * 0.999995000037499687f;   // 1/sqrt(1+1e-5)
    sy[l] = fmaxf((part[0][l] + part[1][l]) * scale + bnb[co], 0.f);
  }
  __syncthreads();
  float accp = (h == 0) ? plb[l] : 0.f;
  #pragma unroll 4
  for (int lq = 0; lq < 256; ++lq) {
    int ll = h*256 + lq;
    accp += sy[ll] * plwT[ll*LL + l];
  }
  part[h][l] = accp;
  __syncthreads();
  if (h == 0)
    out[((b*CC + co)*TT + (TT-1))*LL + l] = xm8[bc*LL + l] - (part[0][l] + part[1][l]);
}

extern "C" void kernel_launch(void* const* d_in, const int* in_sizes, int n_in,
                              void* d_out, int out_size, void* d_ws, size_t ws_size,
                              hipStream_t stream) {
  const float* x    = (const float*)d_in[0];
  const float* Wq   = (const float*)d_in[1];
  const float* bq   = (const float*)d_in[2];
  const float* Wk   = (const float*)d_in[3];
  const float* bk   = (const float*)d_in[4];
  const float* Wv   = (const float*)d_in[5];
  const float* bv   = (const float*)d_in[6];
  const float* Wm   = (const float*)d_in[7];
  const float* bm   = (const float*)d_in[8];
  const float* Wl   = (const float*)d_in[9];
  const float* Wc   = (const float*)d_in[10];
  const float* rpb  = (const float*)d_in[11];
  const float* pp   = (const float*)d_in[12];
  const float* cw   = (const float*)d_in[13];
  const float* cb   = (const float*)d_in[14];
  const float* bng  = (const float*)d_in[15];
  const float* bnb  = (const float*)d_in[16];
  const float* plw  = (const float*)d_in[17];
  const float* plb  = (const float*)d_in[18];
  float* out = (float*)d_out;

  float* ws = (float*)d_ws;
  const size_t NE = (size_t)NBT*LL*CC;         // 1179648
  float* q_ws   = ws;                          // NE fp32 [bt][l][32]
  float* vb_ws  = q_ws + NE;                   // NE fp32 [bt][l][32]
  short* kb_ws  = (short*)(vb_ws + NE);        // NE bf16 [bt][l][32]
  short* vt_ws  = kb_ws + NE;                  // NE bf16 [bt][32][512]
  float* xm8    = (float*)(vt_ws + NE);        // 131072
  float* plwT   = xm8 + (size_t)BB*CC*LL;      // 262144
  float* mbias  = plwT + (size_t)LL*LL;        // 8*1024

  mixed_bias_kernel<<<2, 512, 0, stream>>>(rpb, Wl, mbias);
  transpose512_kernel<<<dim3(16,16), 256, 0, stream>>>(plw, plwT);
  proj_kernel<<<dim3(144,4), 256, 0, stream>>>(x, Wq, bq, Wk, bk, Wv, bv,
                                               q_ws, kb_ws, vb_ws);
  vbt_kernel<<<dim3(NBT,4), 256, 0, stream>>>(vb_ws, vt_ws);
  attn_kernel<<<NBT*32, 256, 0, stream>>>(q_ws, kb_ws, vt_ws, Wl, Wc, mbias,
                                          Wm, bm, out, xm8);
  convpl_kernel<<<BB*CC, 1024, 0, stream>>>(out, pp, cw, cb, bng, bnb,
                                            plwT, plb, xm8, out);
}

// Round 15
// 108.386 us; speedup vs baseline: 1.1409x; 1.1409x over previous
//
#include <hip/hip_runtime.h>
#include <math.h>

#define BB 8
#define CC 32
#define TT 9
#define LL 512
#define HH 8
#define DD 4
#define NBT (BB*TT)          // 72
#define RELN (2*LL-1)        // 1023
#define RLN2 1.4426950408889634f

typedef float  f4v __attribute__((ext_vector_type(4)));
typedef int    i4v __attribute__((ext_vector_type(4)));
typedef short  s8v __attribute__((ext_vector_type(8)));   // 8 bf16 = 4 VGPRs

#define EXP2(x) __builtin_amdgcn_exp2f(x)   // raw v_exp_f32 (exp2f -> OCML call)

__device__ __forceinline__ unsigned cvtpk(float lo, float hi) {
  unsigned u;
  asm("v_cvt_pk_bf16_f32 %0, %1, %2" : "=v"(u) : "v"(lo), "v"(hi));
  return u;
}

// ---------------- prep: transpose pl_w (blocks 0..255) + mixed bias (blocks 256..259) ----
// mbr[Ho][x] = log2e * sum_h rpb[h][1022-x] * Wl[h][Ho]   (x = j - i + 511)
__global__ __launch_bounds__(256) void prep_kernel(
    const float* __restrict__ plw, float* __restrict__ plwT,
    const float* __restrict__ rpb, const float* __restrict__ Wl,
    float* __restrict__ mbr) {
  if (blockIdx.x < 256) {
    __shared__ float tile[32][33];
    int bx = (blockIdx.x & 15) * 32, by = (blockIdx.x >> 4) * 32;
    int tx = threadIdx.x & 31, ty = threadIdx.x >> 5;   // 32x8
    #pragma unroll
    for (int yy = ty; yy < 32; yy += 8)
      tile[yy][tx] = plw[(by + yy)*LL + bx + tx];
    __syncthreads();
    #pragma unroll
    for (int yy = ty; yy < 32; yy += 8)
      plwT[(bx + yy)*LL + by + tx] = tile[tx][yy];
  } else {
    int x = (blockIdx.x - 256) * 256 + threadIdx.x;
    if (x >= RELN) return;
    int idx = 1022 - x;
    float r[HH];
    #pragma unroll
    for (int h = 0; h < HH; ++h) r[h] = rpb[h*RELN + idx];
    #pragma unroll
    for (int Ho = 0; Ho < HH; ++Ho) {
      float acc = 0.f;
      #pragma unroll
      for (int h = 0; h < HH; ++h) acc += r[h] * Wl[h*HH + Ho];
      mbr[Ho*1024 + x] = RLN2 * acc;
    }
  }
}

// ---------------- q/k/v projection + l2norm (4-way co-split); V^T written directly ------
// q fp32 [bt][l][32] scaled by 0.5*log2e; kb bf16 [bt][l][32]; vt bf16 [bt][c][l].
__global__ __launch_bounds__(256) void proj_kernel(
    const float* __restrict__ x,
    const float* __restrict__ Wq, const float* __restrict__ bq,
    const float* __restrict__ Wk, const float* __restrict__ bk,
    const float* __restrict__ Wv, const float* __restrict__ bv,
    float* __restrict__ qo, short* __restrict__ kbo, short* __restrict__ vt) {
  int gidx = blockIdx.x * 256 + threadIdx.x;    // 0..36863
  int l  = gidx & (LL-1);
  int bt = gidx >> 9;
  int b = bt / TT, t = bt - b*TT;
  const int hq = blockIdx.y * 2;

  float xv[CC];
  #pragma unroll
  for (int c = 0; c < CC; ++c)
    xv[c] = x[((b*CC + c)*TT + t)*LL + l];

  // Q (scaled by 0.5*log2e)
  #pragma unroll
  for (int h = hq; h < hq + 2; ++h) {
    float yv[DD];
    #pragma unroll
    for (int d = 0; d < DD; ++d) {
      int co = h*DD + d;
      float acc = bq[co];
      #pragma unroll
      for (int ci = 0; ci < CC; ++ci) acc += xv[ci] * Wq[co*CC + ci];
      yv[d] = acc;
    }
    float n = sqrtf(yv[0]*yv[0] + yv[1]*yv[1] + yv[2]*yv[2] + yv[3]*yv[3]);
    float inv = 0.5f * RLN2 / fmaxf(n, 1e-12f);
    *reinterpret_cast<float4*>(&qo[((size_t)bt*LL + l)*CC + h*DD]) =
        make_float4(yv[0]*inv, yv[1]*inv, yv[2]*inv, yv[3]*inv);
  }
  // K -> bf16 [bt][l][32]
  {
    unsigned ku[4];
    #pragma unroll
    for (int hh = 0; hh < 2; ++hh) {
      int h = hq + hh;
      float yv[DD];
      #pragma unroll
      for (int d = 0; d < DD; ++d) {
        int co = h*DD + d;
        float acc = bk[co];
        #pragma unroll
        for (int ci = 0; ci < CC; ++ci) acc += xv[ci] * Wk[co*CC + ci];
        yv[d] = acc;
      }
      float n = sqrtf(yv[0]*yv[0] + yv[1]*yv[1] + yv[2]*yv[2] + yv[3]*yv[3]);
      float inv = 1.0f / fmaxf(n, 1e-12f);
      ku[hh*2]   = cvtpk(yv[0]*inv, yv[1]*inv);
      ku[hh*2+1] = cvtpk(yv[2]*inv, yv[3]*inv);
    }
    *reinterpret_cast<uint4*>(kbo + ((size_t)bt*LL + l)*CC + hq*DD) =
        make_uint4(ku[0], ku[1], ku[2], ku[3]);
  }
  // V -> bf16 transposed: vt[bt][c][l] (coalesced 2B stores over l)
  #pragma unroll
  for (int h = hq; h < hq + 2; ++h) {
    float yv[DD];
    #pragma unroll
    for (int d = 0; d < DD; ++d) {
      int co = h*DD + d;
      float acc = bv[co];
      #pragma unroll
      for (int ci = 0; ci < CC; ++ci) acc += xv[ci] * Wv[co*CC + ci];
      yv[d] = acc;
    }
    float n = sqrtf(yv[0]*yv[0] + yv[1]*yv[1] + yv[2]*yv[2] + yv[3]*yv[3]);
    float inv = 1.0f / fmaxf(n, 1e-12f);
    #pragma unroll
    for (int d = 0; d < DD; ++d) {
      unsigned u = cvtpk(yv[d]*inv, yv[d]*inv);
      int co = h*DD + d;
      reinterpret_cast<unsigned short*>(vt)[((size_t)bt*CC + co)*LL + l] =
          (unsigned short)(u & 0xffffu);
    }
  }
}

// ---------------- fused attention + Wm (v13 exact — 66.6 us proven) ----------------
__global__ __launch_bounds__(256, 2) void attn_kernel(
    const float* __restrict__ q, const short* __restrict__ kb,
    const short* __restrict__ vt,
    const float* __restrict__ Wl, const float* __restrict__ Wc,
    const float* __restrict__ mbr,
    const float* __restrict__ Wm, const float* __restrict__ bm,
    float* __restrict__ out, float* __restrict__ xm8) {
  __shared__ float xch[2][64][9];   // H-hi partials, padded
  __shared__ float xt[32][33];      // x_att tile, padded
  __shared__ float sWm[32][33];     // Wm[co][ci], padded
  __shared__ float sbm[32];

  const int wgid = blockIdx.x;
  const int id   = (wgid & 7) * 144 + (wgid >> 3);   // 1152 % 8 == 0 -> bijective
  const int bt   = id >> 4;       // [0,72)
  const int iblk = id & 15;       // 32-row block
  const int b    = bt / TT, t = bt - b*TT;

  const int tid  = threadIdx.x;
  const int w    = __builtin_amdgcn_readfirstlane(tid >> 6);
  const int lane = tid & 63;
  const int g    = lane >> 4;     // 0..3
  const int c16  = lane & 15;
  const int it   = iblk*32 + (w & 1)*16;   // wave's i-tile base
  const int Hb   = (w >> 1)*4;

  // preload Wm/bm -> LDS (visible after first barrier)
  {
    int c4 = tid * 4;               // 0..1023
    int co = c4 >> 5, ci = c4 & 31;
    float4 wv = *reinterpret_cast<const float4*>(Wm + co*CC + ci);
    sWm[co][ci] = wv.x; sWm[co][ci+1] = wv.y; sWm[co][ci+2] = wv.z; sWm[co][ci+3] = wv.w;
    if (tid < 32) sbm[tid] = bm[tid];
  }

  // build 4 QM b-frags: B[k=c][n=i] = Wl[h(c)][H] * q[i][c]
  s8v bq4[4];
  {
    float qp[8];
    const float* qr = q + ((size_t)bt*LL + it + c16)*CC + g*8;
    float4 qa = *reinterpret_cast<const float4*>(qr);
    float4 qb = *reinterpret_cast<const float4*>(qr + 4);
    qp[0]=qa.x; qp[1]=qa.y; qp[2]=qa.z; qp[3]=qa.w;
    qp[4]=qb.x; qp[5]=qb.y; qp[6]=qb.z; qp[7]=qb.w;
    const int h0 = g*2;
    #pragma unroll
    for (int hh = 0; hh < 4; ++hh) {
      const int H = Hb + hh;
      const float wla = Wl[h0*HH + H];
      const float wlb = Wl[(h0+1)*HH + H];
      i4v uq;
      uq[0] = (int)cvtpk(qp[0]*wla, qp[1]*wla);
      uq[1] = (int)cvtpk(qp[2]*wla, qp[3]*wla);
      uq[2] = (int)cvtpk(qp[4]*wlb, qp[5]*wlb);
      uq[3] = (int)cvtpk(qp[6]*wlb, qp[7]*wlb);
      bq4[hh] = __builtin_bit_cast(s8v, uq);
    }
  }

  const short* kbase = kb + ((size_t)bt*LL)*CC + (size_t)c16*CC + g*8;
  const short* vb0 = vt + ((size_t)bt*CC)*LL + (size_t)c16*LL + 8*g;
  const short* vb1 = vb0 + 16*LL;
  const float* mbase = mbr + Hb*1024 + 511 + 4*g - it - c16;

  f4v t0[4], t1[4];
  float den[4];
  #pragma unroll
  for (int hh = 0; hh < 4; ++hh) {
    t0[hh] = (f4v){0.f,0.f,0.f,0.f};
    t1[hh] = (f4v){0.f,0.f,0.f,0.f};
    den[hh] = 0.f;
  }

  const int s0b = (c16 + 32*(g & 1))*4;    // bpermute byte addrs
  const int s1b = s0b + 64;
  const bool useA = (g < 2);

  #pragma unroll 1
  for (int jp = 0; jp < 16; ++jp) {
    const int j0 = jp*32;
    s8v ak0 = *reinterpret_cast<const s8v*>(kbase + (size_t)j0*CC);
    s8v ak1 = *reinterpret_cast<const s8v*>(kbase + (size_t)(j0+16)*CC);
    s8v v0  = *reinterpret_cast<const s8v*>(vb0 + j0);
    s8v v1  = *reinterpret_cast<const s8v*>(vb1 + j0);

    #pragma unroll
    for (int hh = 0; hh < 4; ++hh) {
      const float* m = mbase + hh*1024 + j0;
      unsigned uA0, uA1, uB0, uB1;
      {
        f4v cb = { m[0], m[1], m[2], m[3] };
        f4v d = __builtin_amdgcn_mfma_f32_16x16x32_bf16(ak0, bq4[hh], cb, 0, 0, 0);
        float e0 = EXP2(d[0]), e1 = EXP2(d[1]), e2 = EXP2(d[2]), e3 = EXP2(d[3]);
        den[hh] += (e0 + e1) + (e2 + e3);
        uA0 = cvtpk(e0, e1); uA1 = cvtpk(e2, e3);
      }
      {
        f4v cb = { m[16], m[17], m[18], m[19] };
        f4v d = __builtin_amdgcn_mfma_f32_16x16x32_bf16(ak1, bq4[hh], cb, 0, 0, 0);
        float e0 = EXP2(d[0]), e1 = EXP2(d[1]), e2 = EXP2(d[2]), e3 = EXP2(d[3]);
        den[hh] += (e0 + e1) + (e2 + e3);
        uB0 = cvtpk(e0, e1); uB1 = cvtpk(e2, e3);
      }
      int a00 = __builtin_amdgcn_ds_bpermute(s0b, (int)uA0);
      int b00 = __builtin_amdgcn_ds_bpermute(s0b, (int)uB0);
      int a01 = __builtin_amdgcn_ds_bpermute(s0b, (int)uA1);
      int b01 = __builtin_amdgcn_ds_bpermute(s0b, (int)uB1);
      int a10 = __builtin_amdgcn_ds_bpermute(s1b, (int)uA0);
      int b10 = __builtin_amdgcn_ds_bpermute(s1b, (int)uB0);
      int a11 = __builtin_amdgcn_ds_bpermute(s1b, (int)uA1);
      int b11 = __builtin_amdgcn_ds_bpermute(s1b, (int)uB1);
      i4v pv;
      pv[0] = useA ? a00 : b00;
      pv[1] = useA ? a01 : b01;
      pv[2] = useA ? a10 : b10;
      pv[3] = useA ? a11 : b11;
      s8v pa = __builtin_bit_cast(s8v, pv);
      t0[hh] = __builtin_amdgcn_mfma_f32_16x16x32_bf16(pa, v0, t0[hh], 0, 0, 0);
      t1[hh] = __builtin_amdgcn_mfma_f32_16x16x32_bf16(pa, v1, t1[hh], 0, 0, 0);
    }
  }

  // epilogue: per head, reduce denominator and fold Wc/S scale
  f4v fin0 = {0.f,0.f,0.f,0.f}, fin1 = {0.f,0.f,0.f,0.f};
  #pragma unroll
  for (int hh = 0; hh < 4; ++hh) {
    const int H = Hb + hh;
    float dn = den[hh];
    dn += __shfl_xor(dn, 16);
    dn += __shfl_xor(dn, 32);
    float inv = __builtin_amdgcn_rcpf(dn);
    const float wclo = Wc[H*HH + (c16 >> 2)];
    const float wchi = Wc[H*HH + 4 + (c16 >> 2)];
    #pragma unroll
    for (int r = 0; r < 4; ++r) {
      float ir = __int_as_float(
          __builtin_amdgcn_ds_bpermute((4*g + r)*4, __float_as_int(inv)));
      fin0[r] += t0[hh][r] * (ir * wclo);
      fin1[r] += t1[hh][r] * (ir * wchi);
    }
  }

  // combine H-halves (waves 2,3 -> 0,1)
  if (w >= 2) {
    #pragma unroll
    for (int r = 0; r < 4; ++r) {
      xch[w-2][lane][r]     = fin0[r];
      xch[w-2][lane][4 + r] = fin1[r];
    }
  }
  __syncthreads();
  if (w < 2) {
    #pragma unroll
    for (int r = 0; r < 4; ++r) {
      float o0 = fin0[r] + xch[w][lane][r];
      float o1 = fin1[r] + xch[w][lane][4 + r];
      const int row = w*16 + 4*g + r;    // w<2: w == (w&1)
      xt[row][c16]      = o0;
      xt[row][16 + c16] = o1;
    }
  }
  __syncthreads();

  // in-block Wm: 1024 outputs over 256 threads (4 co each, one row)
  {
    const int row = tid & 31;
    const int cos = (tid >> 5) * 4;
    float a0 = sbm[cos], a1 = sbm[cos+1], a2 = sbm[cos+2], a3 = sbm[cos+3];
    #pragma unroll
    for (int c = 0; c < CC; ++c) {
      float xv = xt[row][c];
      a0 += xv * sWm[cos][c];
      a1 += xv * sWm[cos+1][c];
      a2 += xv * sWm[cos+2][c];
      a3 += xv * sWm[cos+3][c];
    }
    const int l = iblk*32 + row;
    float av[4] = {a0, a1, a2, a3};
    #pragma unroll
    for (int u = 0; u < 4; ++u) {
      int co = cos + u;
      if (t < TT-1) out[((b*CC + co)*TT + t)*LL + l] = av[u];
      else          xm8[(b*CC + co)*LL + l] = av[u];
    }
  }
}

// ---------------- fused conv+BN+ReLU+token-linear+subtract (1024 thr, 2-way split) --------
__global__ __launch_bounds__(1024) void convpl_kernel(
    const float* __restrict__ out_in, const float* __restrict__ pp,
    const float* __restrict__ cw, const float* __restrict__ cb,
    const float* __restrict__ bng, const float* __restrict__ bnb,
    const float* __restrict__ plwT, const float* __restrict__ plb,
    const float* __restrict__ xm8, float* __restrict__ out) {
  __shared__ float sy[LL];
  __shared__ float part[2][LL];
  int bc = blockIdx.x;            // b*32 + co
  int b = bc >> 5, co = bc & 31;
  int tid = threadIdx.x;
  int l = tid & (LL-1);
  int h = tid >> 9;               // 0,1

  float acc = (h == 0) ? cb[co] : 0.f;
  #pragma unroll
  for (int cc = 0; cc < 16; ++cc) {
    int ci = h*16 + cc;
    const float* base = out_in + ((b*CC + ci)*TT)*LL + l;
    const float* wv = cw + (co*CC + ci)*TT;
    #pragma unroll
    for (int tq = 0; tq < TT-1; ++tq) acc += base[tq*LL] * wv[tq];
    acc += pp[ci*LL + l] * wv[TT-1];
  }
  part[h][l] = acc;
  __syncthreads();
  if (h == 0) {
    float scale = bng[co] * 0.999995000037499687f;   // 1/sqrt(1+1e-5)
    sy[l] = fmaxf((part[0][l] + part[1][l]) * scale + bnb[co], 0.f);
  }
  __syncthreads();
  float accp = (h == 0) ? plb[l] : 0.f;
  #pragma unroll 4
  for (int lq = 0; lq < 256; ++lq) {
    int ll = h*256 + lq;
    accp += sy[ll] * plwT[ll*LL + l];
  }
  part[h][l] = accp;
  __syncthreads();
  if (h == 0)
    out[((b*CC + co)*TT + (TT-1))*LL + l] = xm8[bc*LL + l] - (part[0][l] + part[1][l]);
}

extern "C" void kernel_launch(void* const* d_in, const int* in_sizes, int n_in,
                              void* d_out, int out_size, void* d_ws, size_t ws_size,
                              hipStream_t stream) {
  const float* x    = (const float*)d_in[0];
  const float* Wq   = (const float*)d_in[1];
  const float* bq   = (const float*)d_in[2];
  const float* Wk   = (const float*)d_in[3];
  const float* bk   = (const float*)d_in[4];
  const float* Wv   = (const float*)d_in[5];
  const float* bv   = (const float*)d_in[6];
  const float* Wm   = (const float*)d_in[7];
  const float* bm   = (const float*)d_in[8];
  const float* Wl   = (const float*)d_in[9];
  const float* Wc   = (const float*)d_in[10];
  const float* rpb  = (const float*)d_in[11];
  const float* pp   = (const float*)d_in[12];
  const float* cw   = (const float*)d_in[13];
  const float* cb   = (const float*)d_in[14];
  const float* bng  = (const float*)d_in[15];
  const float* bnb  = (const float*)d_in[16];
  const float* plw  = (const float*)d_in[17];
  const float* plb  = (const float*)d_in[18];
  float* out = (float*)d_out;

  float* ws = (float*)d_ws;
  const size_t NE = (size_t)NBT*LL*CC;         // 1179648
  float* q_ws   = ws;                          // NE fp32 [bt][l][32]
  short* kb_ws  = (short*)(q_ws + NE);         // NE bf16 [bt][l][32]
  short* vt_ws  = kb_ws + NE;                  // NE bf16 [bt][32][512]
  float* xm8    = (float*)(vt_ws + NE);        // 131072
  float* plwT   = xm8 + (size_t)BB*CC*LL;      // 262144
  float* mbias  = plwT + (size_t)LL*LL;        // 8*1024

  prep_kernel<<<260, 256, 0, stream>>>(plw, plwT, rpb, Wl, mbias);
  proj_kernel<<<dim3(144,4), 256, 0, stream>>>(x, Wq, bq, Wk, bk, Wv, bv,
                                               q_ws, kb_ws, vt_ws);
  attn_kernel<<<NBT*16, 256, 0, stream>>>(q_ws, kb_ws, vt_ws, Wl, Wc, mbias,
                                          Wm, bm, out, xm8);
  convpl_kernel<<<BB*CC, 1024, 0, stream>>>(out, pp, cw, cb, bng, bnb,
                                            plwT, plb, xm8, out);
}